// Round 2
// baseline (858.967 us; speedup 1.0000x reference)
//
#include <hip/hip_runtime.h>

#define D 128

typedef __attribute__((ext_vector_type(8))) short bf16x8;
typedef __attribute__((ext_vector_type(4))) float floatx4;

__device__ __forceinline__ unsigned int f2bfbits(float f){
    unsigned int x = __float_as_uint(f);
    return (x + 0x7fffu + ((x >> 16) & 1u)) >> 16;  // RNE, finite inputs
}

// ---- degree histogram over dst (self-loop added later as +1) ----
__global__ __launch_bounds__(256) void k_deg(const int* __restrict__ dst, int* __restrict__ deg, int E){
    int i = blockIdx.x * 256 + threadIdx.x;
    if (i < E) atomicAdd(&deg[dst[i]], 1);
}

__global__ __launch_bounds__(256) void k_dinv(const int* __restrict__ deg, float* __restrict__ dinv, int N){
    int i = blockIdx.x * 256 + threadIdx.x;
    if (i < N) dinv[i] = rsqrtf((float)deg[i] + 1.0f);  // +1 = self-loop; always > 0
}

// ---- single-block exclusive scan of deg -> rowStart (+ cursor copy) ----
__global__ __launch_bounds__(1024) void k_scan(const int* __restrict__ deg, int* __restrict__ rowStart,
                                               int* __restrict__ cursor, int N){
    __shared__ int sm[1024];
    int t = threadIdx.x;
    int C = (N + 1023) >> 10;
    int lo = t * C, hi = min(lo + C, N);
    int s = 0;
    for (int i = lo; i < hi; ++i) s += deg[i];
    sm[t] = s; __syncthreads();
    for (int off = 1; off < 1024; off <<= 1){
        int v = (t >= off) ? sm[t - off] : 0;
        __syncthreads();
        sm[t] += v;
        __syncthreads();
    }
    int run = (t > 0) ? sm[t - 1] : 0;
    for (int i = lo; i < hi; ++i){
        rowStart[i] = run; cursor[i] = run;
        run += deg[i];
    }
    if (t == 1023) rowStart[N] = sm[1023];
}

// ---- scatter edges into CSR slots ----
__global__ __launch_bounds__(256) void k_scatter(const int* __restrict__ src, const int* __restrict__ dst,
                                                 int* __restrict__ cursor, int* __restrict__ csr, int E){
    int i = blockIdx.x * 256 + threadIdx.x;
    if (i < E){
        int d = dst[i];
        int pos = atomicAdd(&cursor[d], 1);
        csr[pos] = src[i];
    }
}

// ---- transpose + fp32->bf16 both weight matrices: Wt[n][k] = bf16(W[k][n]) ----
__global__ __launch_bounds__(256) void k_wtrans(const float* __restrict__ W1,
                                                const float* __restrict__ W2,
                                                unsigned short* __restrict__ Wt1,
                                                unsigned short* __restrict__ Wt2){
    int i = blockIdx.x * 256 + threadIdx.x;  // 0..32767
    const float* Ws; unsigned short* Wd; int j = i;
    if (i < 16384){ Ws = W1; Wd = Wt1; } else { Ws = W2; Wd = Wt2; j -= 16384; }
    int k = j >> 7, n = j & 127;
    Wd[n * 128 + k] = (unsigned short)f2bfbits(Ws[k * 128 + n]);
}

// ---- bf16 MFMA GEMM: H[N x 128] = bf16(A[N x 128]) @ bf16(W), H stored fp32 ----
// A is fp32; Wt = W^T in bf16 (row n holds k=0..127).
// block = 4 waves, each wave computes a 16 x 128 strip via 16x16x32 MFMA.
__global__ __launch_bounds__(256) void k_gemm(const float* __restrict__ A,
                                              const unsigned short* __restrict__ Wt,
                                              float* __restrict__ Hout, int Nrows){
    int wave = threadIdx.x >> 6, lane = threadIdx.x & 63;
    int m = lane & 15, quad = lane >> 4;
    int row0 = blockIdx.x * 64 + wave * 16;
    int arow = row0 + m;
    int arowc = arow < Nrows ? arow : Nrows - 1;  // clamp loads; stores guarded

    // A fragment: A[m = lane&15][k = quad*8 + j], per 32-wide K tile kt
    bf16x8 a[4];
    const float* Ap = A + (size_t)arowc * D + quad * 8;
#pragma unroll
    for (int kt = 0; kt < 4; ++kt){
        float4 v0 = *(const float4*)(Ap + kt * 32);
        float4 v1 = *(const float4*)(Ap + kt * 32 + 4);
        bf16x8 af;
        af[0] = (short)f2bfbits(v0.x); af[1] = (short)f2bfbits(v0.y);
        af[2] = (short)f2bfbits(v0.z); af[3] = (short)f2bfbits(v0.w);
        af[4] = (short)f2bfbits(v1.x); af[5] = (short)f2bfbits(v1.y);
        af[6] = (short)f2bfbits(v1.z); af[7] = (short)f2bfbits(v1.w);
        a[kt] = af;
    }

    floatx4 acc[8];
#pragma unroll
    for (int nt = 0; nt < 8; ++nt) acc[nt] = (floatx4){0.f, 0.f, 0.f, 0.f};

    // B fragment: B[k = quad*8 + j][n = lane&15] = Wt[n][k]
    const unsigned short* Bp = Wt + m * D + quad * 8;
#pragma unroll
    for (int kt = 0; kt < 4; ++kt){
        bf16x8 bk[8];
#pragma unroll
        for (int nt = 0; nt < 8; ++nt) bk[nt] = *(const bf16x8*)(Bp + nt * 16 * D + kt * 32);
#pragma unroll
        for (int nt = 0; nt < 8; ++nt)
            acc[nt] = __builtin_amdgcn_mfma_f32_16x16x32_bf16(a[kt], bk[nt], acc[nt], 0, 0, 0);
    }
    // C/D layout: col = lane&15, row = quad*4 + r  [verified m89]
#pragma unroll
    for (int nt = 0; nt < 8; ++nt){
#pragma unroll
        for (int r = 0; r < 4; ++r){
            int rr = row0 + quad * 4 + r;
            if (rr < Nrows) Hout[(size_t)rr * D + nt * 16 + m] = acc[nt][r];
        }
    }
}

// ---- fused gather-aggregate + bias + LayerNorm + ReLU; one wave per node ----
__global__ __launch_bounds__(256) void k_agg(const float* __restrict__ h,
                                             const int* __restrict__ rowStart,
                                             const int* __restrict__ csr,
                                             const float* __restrict__ dinv,
                                             const float* __restrict__ bias,
                                             const float* __restrict__ gamma,
                                             const float* __restrict__ beta,
                                             float* __restrict__ out, int N){
    int node = blockIdx.x * 4 + (threadIdx.x >> 6);
    if (node >= N) return;  // wave-uniform exit
    int lane = threadIdx.x & 63;
    const float2* hv = (const float2*)h;  // lane owns channels 2l, 2l+1

    float dv = dinv[node];
    float2 hself = hv[(size_t)node * 64 + lane];
    float w0 = dv * dv;  // self-loop norm
    float accx = hself.x * w0, accy = hself.y * w0;

    int e = rowStart[node], end = rowStart[node + 1];
    int s_next = (e < end) ? csr[e] : 0;
    while (e < end){
        int s = s_next;
        ++e;
        if (e < end) s_next = csr[e];  // prefetch next src id
        float ws = dinv[s] * dv;
        float2 hs = hv[(size_t)s * 64 + lane];
        accx = fmaf(hs.x, ws, accx);
        accy = fmaf(hs.y, ws, accy);
    }
    float2 bb = ((const float2*)bias)[lane];
    accx += bb.x; accy += bb.y;

    // LayerNorm across 128 channels: wave butterfly reduce of (sum, sumsq)
    float s1 = accx + accy, s2 = accx * accx + accy * accy;
#pragma unroll
    for (int off = 32; off > 0; off >>= 1){
        s1 += __shfl_xor(s1, off, 64);
        s2 += __shfl_xor(s2, off, 64);
    }
    float mu = s1 * (1.0f / 128.0f);
    float var = s2 * (1.0f / 128.0f) - mu * mu;
    float rstd = rsqrtf(var + 1e-5f);

    float2 gg = ((const float2*)gamma)[lane];
    float2 be = ((const float2*)beta)[lane];
    float ox = fmaxf(fmaf((accx - mu) * rstd, gg.x, be.x), 0.0f);
    float oy = fmaxf(fmaf((accy - mu) * rstd, gg.y, be.y), 0.0f);
    float2 o; o.x = ox; o.y = oy;
    ((float2*)out)[(size_t)node * 64 + lane] = o;
}

extern "C" void kernel_launch(void* const* d_in, const int* in_sizes, int n_in,
                              void* d_out, int out_size, void* d_ws, size_t ws_size,
                              hipStream_t stream){
    const float* x   = (const float*)d_in[0];
    const int*   ei  = (const int*)d_in[1];
    const float* W1  = (const float*)d_in[2];
    const float* b1  = (const float*)d_in[3];
    const float* g1  = (const float*)d_in[4];
    const float* be1 = (const float*)d_in[5];
    const float* W2  = (const float*)d_in[6];
    const float* b2  = (const float*)d_in[7];
    const float* g2  = (const float*)d_in[8];
    const float* be2 = (const float*)d_in[9];
    float* out = (float*)d_out;

    const int N = in_sizes[0] / D;
    const int E = in_sizes[1] / 2;
    const int* src = ei;
    const int* dst = ei + E;

    // workspace carve-out (256B-aligned)
    char* w = (char*)d_ws;
    size_t off = 0;
    auto alloc = [&](size_t bytes) -> char* {
        char* p = w + off;
        off = (off + bytes + 255) & ~(size_t)255;
        return p;
    };
    int*            deg      = (int*)alloc((size_t)N * 4);
    float*          dinv     = (float*)alloc((size_t)N * 4);
    int*            rowStart = (int*)alloc((size_t)(N + 1) * 4);
    int*            cursor   = (int*)alloc((size_t)N * 4);
    int*            csr      = (int*)alloc((size_t)E * 4);
    unsigned short* wt1      = (unsigned short*)alloc(16384 * 2);
    unsigned short* wt2      = (unsigned short*)alloc(16384 * 2);
    float*          h        = (float*)alloc((size_t)N * D * 4);
    float*          hpost    = out;  // reuse d_out as layer-1 activation buffer

    (void)hipMemsetAsync(deg, 0, (size_t)N * 4, stream);

    int gE = (E + 255) / 256;
    int gN = (N + 255) / 256;
    int gG = (N + 63) / 64;
    int gA = (N + 3) / 4;

    k_deg    <<<gE, 256, 0, stream>>>(dst, deg, E);
    k_dinv   <<<gN, 256, 0, stream>>>(deg, dinv, N);
    k_scan   <<<1, 1024, 0, stream>>>(deg, rowStart, cursor, N);
    k_scatter<<<gE, 256, 0, stream>>>(src, dst, cursor, csr, E);
    k_wtrans <<<128, 256, 0, stream>>>(W1, W2, wt1, wt2);

    // layer 1
    k_gemm<<<gG, 256, 0, stream>>>(x, wt1, h, N);
    k_agg <<<gA, 256, 0, stream>>>(h, rowStart, csr, dinv, b1, g1, be1, hpost, N);
    // layer 2
    k_gemm<<<gG, 256, 0, stream>>>(hpost, wt2, h, N);
    k_agg <<<gA, 256, 0, stream>>>(h, rowStart, csr, dinv, b2, g2, be2, out, N);
}

// Round 3
// 627.409 us; speedup vs baseline: 1.3691x; 1.3691x over previous
//
#include <hip/hip_runtime.h>

#define D 128

typedef __attribute__((ext_vector_type(8))) short bf16x8;
typedef __attribute__((ext_vector_type(4))) float floatx4;

__device__ __forceinline__ unsigned int f2bfbits(float f){
    unsigned int x = __float_as_uint(f);
    return (x + 0x7fffu + ((x >> 16) & 1u)) >> 16;  // RNE, finite inputs
}

// ---- degree histogram over dst (self-loop added later as +1) ----
__global__ __launch_bounds__(256) void k_deg(const int* __restrict__ dst, int* __restrict__ deg, int E){
    int i = blockIdx.x * 256 + threadIdx.x;
    if (i < E) atomicAdd(&deg[dst[i]], 1);
}

__global__ __launch_bounds__(256) void k_dinv(const int* __restrict__ deg, float* __restrict__ dinv, int N){
    int i = blockIdx.x * 256 + threadIdx.x;
    if (i < N) dinv[i] = rsqrtf((float)deg[i] + 1.0f);  // +1 = self-loop; always > 0
}

// ======== device-wide exclusive scan of deg (3 small kernels) ========
// chunk = 2048 elements per block (256 threads x 8)

__global__ __launch_bounds__(256) void k_part(const int* __restrict__ deg, int* __restrict__ bsum, int N){
    int b = blockIdx.x, t = threadIdx.x;
    int base = b * 2048 + t * 8;
    int s = 0;
#pragma unroll
    for (int j = 0; j < 8; ++j) s += (base + j < N) ? deg[base + j] : 0;
#pragma unroll
    for (int off = 32; off > 0; off >>= 1) s += __shfl_xor(s, off, 64);
    __shared__ int sm[4];
    if ((t & 63) == 0) sm[t >> 6] = s;
    __syncthreads();
    if (t == 0) bsum[b] = sm[0] + sm[1] + sm[2] + sm[3];
}

// single tiny block: in-place exclusive scan of nb block sums; writes rowStart[N]=total
__global__ __launch_bounds__(256) void k_ssum(int* __restrict__ bsum, int nb, int* __restrict__ rowStartN){
    __shared__ int sm[256];
    int t = threadIdx.x;
    int C = (nb + 255) >> 8;
    int lo = t * C, hi = min(lo + C, nb);
    int s = 0;
    for (int i = lo; i < hi; ++i) s += bsum[i];
    sm[t] = s; __syncthreads();
    for (int off = 1; off < 256; off <<= 1){
        int x = (t >= off) ? sm[t - off] : 0;
        __syncthreads();
        sm[t] += x;
        __syncthreads();
    }
    int run = (t > 0) ? sm[t - 1] : 0;
    for (int i = lo; i < hi; ++i){ int v = bsum[i]; bsum[i] = run; run += v; }
    if (t == 255) *rowStartN = sm[255];
}

__global__ __launch_bounds__(256) void k_final(const int* __restrict__ deg, const int* __restrict__ bsum,
                                               int* __restrict__ rowStart, int* __restrict__ cursor, int N){
    int b = blockIdx.x, t = threadIdx.x;
    int base = b * 2048 + t * 8;
    int v[8]; int tot = 0;
#pragma unroll
    for (int j = 0; j < 8; ++j){ v[j] = (base + j < N) ? deg[base + j] : 0; tot += v[j]; }
    __shared__ int sm[256];
    sm[t] = tot; __syncthreads();
    for (int off = 1; off < 256; off <<= 1){
        int x = (t >= off) ? sm[t - off] : 0;
        __syncthreads();
        sm[t] += x;
        __syncthreads();
    }
    int run = ((t > 0) ? sm[t - 1] : 0) + bsum[b];
#pragma unroll
    for (int j = 0; j < 8; ++j){
        if (base + j < N){ rowStart[base + j] = run; cursor[base + j] = run; run += v[j]; }
    }
}

// ---- scatter edges into CSR slots ----
__global__ __launch_bounds__(256) void k_scatter(const int* __restrict__ src, const int* __restrict__ dst,
                                                 int* __restrict__ cursor, int* __restrict__ csr, int E){
    int i = blockIdx.x * 256 + threadIdx.x;
    if (i < E){
        int d = dst[i];
        int pos = atomicAdd(&cursor[d], 1);
        csr[pos] = src[i];
    }
}

// ---- transpose + fp32->bf16 both weight matrices: Wt[n][k] = bf16(W[k][n]) ----
__global__ __launch_bounds__(256) void k_wtrans(const float* __restrict__ W1,
                                                const float* __restrict__ W2,
                                                unsigned short* __restrict__ Wt1,
                                                unsigned short* __restrict__ Wt2){
    int i = blockIdx.x * 256 + threadIdx.x;  // 0..32767
    const float* Ws; unsigned short* Wd; int j = i;
    if (i < 16384){ Ws = W1; Wd = Wt1; } else { Ws = W2; Wd = Wt2; j -= 16384; }
    int k = j >> 7, n = j & 127;
    Wd[n * 128 + k] = (unsigned short)f2bfbits(Ws[k * 128 + n]);
}

// ---- bf16 MFMA GEMM: H[N x 128] = bf16(A[N x 128]) @ bf16(W), H stored fp32 ----
__global__ __launch_bounds__(256) void k_gemm(const float* __restrict__ A,
                                              const unsigned short* __restrict__ Wt,
                                              float* __restrict__ Hout, int Nrows){
    int wave = threadIdx.x >> 6, lane = threadIdx.x & 63;
    int m = lane & 15, quad = lane >> 4;
    int row0 = blockIdx.x * 64 + wave * 16;
    int arow = row0 + m;
    int arowc = arow < Nrows ? arow : Nrows - 1;  // clamp loads; stores guarded

    bf16x8 a[4];
    const float* Ap = A + (size_t)arowc * D + quad * 8;
#pragma unroll
    for (int kt = 0; kt < 4; ++kt){
        float4 v0 = *(const float4*)(Ap + kt * 32);
        float4 v1 = *(const float4*)(Ap + kt * 32 + 4);
        bf16x8 af;
        af[0] = (short)f2bfbits(v0.x); af[1] = (short)f2bfbits(v0.y);
        af[2] = (short)f2bfbits(v0.z); af[3] = (short)f2bfbits(v0.w);
        af[4] = (short)f2bfbits(v1.x); af[5] = (short)f2bfbits(v1.y);
        af[6] = (short)f2bfbits(v1.z); af[7] = (short)f2bfbits(v1.w);
        a[kt] = af;
    }

    floatx4 acc[8];
#pragma unroll
    for (int nt = 0; nt < 8; ++nt) acc[nt] = (floatx4){0.f, 0.f, 0.f, 0.f};

    const unsigned short* Bp = Wt + m * D + quad * 8;  // B frag: n = lane&15, k = quad*8+j
#pragma unroll
    for (int kt = 0; kt < 4; ++kt){
        bf16x8 bk[8];
#pragma unroll
        for (int nt = 0; nt < 8; ++nt) bk[nt] = *(const bf16x8*)(Bp + nt * 16 * D + kt * 32);
#pragma unroll
        for (int nt = 0; nt < 8; ++nt)
            acc[nt] = __builtin_amdgcn_mfma_f32_16x16x32_bf16(a[kt], bk[nt], acc[nt], 0, 0, 0);
    }
#pragma unroll
    for (int nt = 0; nt < 8; ++nt){
#pragma unroll
        for (int r = 0; r < 4; ++r){
            int rr = row0 + quad * 4 + r;
            if (rr < Nrows) Hout[(size_t)rr * D + nt * 16 + m] = acc[nt][r];
        }
    }
}

// ---- fused gather-aggregate + bias + LayerNorm + ReLU ----
// one wave per node; 2 edges in flight (half-wave per edge, lane owns 4 channels)
__global__ __launch_bounds__(256) void k_agg(const float* __restrict__ h,
                                             const int* __restrict__ rowStart,
                                             const int* __restrict__ csr,
                                             const float* __restrict__ dinv,
                                             const float* __restrict__ bias,
                                             const float* __restrict__ gamma,
                                             const float* __restrict__ beta,
                                             float* __restrict__ out, int N){
    int node = blockIdx.x * 4 + (threadIdx.x >> 6);
    if (node >= N) return;  // wave-uniform exit
    int lane = threadIdx.x & 63;
    int half = lane >> 5, li = lane & 31;   // lane owns channels 4*li..4*li+3
    const float4* hv4 = (const float4*)h;   // 32 float4 per row

    float dv = dinv[node];
    float4 acc = {0.f, 0.f, 0.f, 0.f};
    if (half == 0){
        float4 hs = hv4[(size_t)node * 32 + li];
        float w0 = dv * dv;  // self-loop norm
        acc.x = hs.x * w0; acc.y = hs.y * w0; acc.z = hs.z * w0; acc.w = hs.w * w0;
    }

    int end = rowStart[node + 1];
    int e = rowStart[node] + half;
    int s_next = (e < end) ? csr[e] : 0;
    while (e < end){
        int s = s_next;
        int en = e + 2;
        if (en < end) s_next = csr[en];  // prefetch
        float ws = dinv[s] * dv;
        float4 hs = hv4[(size_t)s * 32 + li];
        acc.x = fmaf(hs.x, ws, acc.x);
        acc.y = fmaf(hs.y, ws, acc.y);
        acc.z = fmaf(hs.z, ws, acc.z);
        acc.w = fmaf(hs.w, ws, acc.w);
        e = en;
    }
    // combine the two half-wave partial sums (lane L <-> L^32 hold same channels)
    acc.x += __shfl_xor(acc.x, 32, 64);
    acc.y += __shfl_xor(acc.y, 32, 64);
    acc.z += __shfl_xor(acc.z, 32, 64);
    acc.w += __shfl_xor(acc.w, 32, 64);

    float4 bb = ((const float4*)bias)[li];
    acc.x += bb.x; acc.y += bb.y; acc.z += bb.z; acc.w += bb.w;

    // LayerNorm: both halves now identical; reduce across 32 lanes
    float s1 = acc.x + acc.y + acc.z + acc.w;
    float s2 = acc.x * acc.x + acc.y * acc.y + acc.z * acc.z + acc.w * acc.w;
#pragma unroll
    for (int off = 16; off > 0; off >>= 1){
        s1 += __shfl_xor(s1, off, 64);
        s2 += __shfl_xor(s2, off, 64);
    }
    float mu = s1 * (1.0f / 128.0f);
    float var = s2 * (1.0f / 128.0f) - mu * mu;
    float rstd = rsqrtf(var + 1e-5f);

    float4 gg = ((const float4*)gamma)[li];
    float4 be = ((const float4*)beta)[li];
    float4 o;
    o.x = fmaxf(fmaf((acc.x - mu) * rstd, gg.x, be.x), 0.0f);
    o.y = fmaxf(fmaf((acc.y - mu) * rstd, gg.y, be.y), 0.0f);
    o.z = fmaxf(fmaf((acc.z - mu) * rstd, gg.z, be.z), 0.0f);
    o.w = fmaxf(fmaf((acc.w - mu) * rstd, gg.w, be.w), 0.0f);
    if (half == 0) ((float4*)out)[(size_t)node * 32 + li] = o;
}

extern "C" void kernel_launch(void* const* d_in, const int* in_sizes, int n_in,
                              void* d_out, int out_size, void* d_ws, size_t ws_size,
                              hipStream_t stream){
    const float* x   = (const float*)d_in[0];
    const int*   ei  = (const int*)d_in[1];
    const float* W1  = (const float*)d_in[2];
    const float* b1  = (const float*)d_in[3];
    const float* g1  = (const float*)d_in[4];
    const float* be1 = (const float*)d_in[5];
    const float* W2  = (const float*)d_in[6];
    const float* b2  = (const float*)d_in[7];
    const float* g2  = (const float*)d_in[8];
    const float* be2 = (const float*)d_in[9];
    float* out = (float*)d_out;

    const int N = in_sizes[0] / D;
    const int E = in_sizes[1] / 2;
    const int* src = ei;
    const int* dst = ei + E;

    char* w = (char*)d_ws;
    size_t off = 0;
    auto alloc = [&](size_t bytes) -> char* {
        char* p = w + off;
        off = (off + bytes + 255) & ~(size_t)255;
        return p;
    };
    const int nchunk = (N + 2047) / 2048;
    int*            deg      = (int*)alloc((size_t)N * 4);
    float*          dinv     = (float*)alloc((size_t)N * 4);
    int*            rowStart = (int*)alloc((size_t)(N + 1) * 4);
    int*            cursor   = (int*)alloc((size_t)N * 4);
    int*            bsum     = (int*)alloc((size_t)nchunk * 4);
    int*            csr      = (int*)alloc((size_t)E * 4);
    unsigned short* wt1      = (unsigned short*)alloc(16384 * 2);
    unsigned short* wt2      = (unsigned short*)alloc(16384 * 2);
    float*          h        = (float*)alloc((size_t)N * D * 4);
    float*          hpost    = out;  // reuse d_out as layer-1 activation buffer

    (void)hipMemsetAsync(deg, 0, (size_t)N * 4, stream);

    int gE = (E + 255) / 256;
    int gN = (N + 255) / 256;
    int gG = (N + 63) / 64;
    int gA = (N + 3) / 4;

    k_deg    <<<gE, 256, 0, stream>>>(dst, deg, E);
    k_dinv   <<<gN, 256, 0, stream>>>(deg, dinv, N);
    k_part   <<<nchunk, 256, 0, stream>>>(deg, bsum, N);
    k_ssum   <<<1, 256, 0, stream>>>(bsum, nchunk, rowStart + N);
    k_final  <<<nchunk, 256, 0, stream>>>(deg, bsum, rowStart, cursor, N);
    k_scatter<<<gE, 256, 0, stream>>>(src, dst, cursor, csr, E);
    k_wtrans <<<128, 256, 0, stream>>>(W1, W2, wt1, wt2);

    // layer 1
    k_gemm<<<gG, 256, 0, stream>>>(x, wt1, h, N);
    k_agg <<<gA, 256, 0, stream>>>(h, rowStart, csr, dinv, b1, g1, be1, hpost, N);
    // layer 2
    k_gemm<<<gG, 256, 0, stream>>>(hpost, wt2, h, N);
    k_agg <<<gA, 256, 0, stream>>>(h, rowStart, csr, dinv, b2, g2, be2, out, N);
}

// Round 4
// 488.280 us; speedup vs baseline: 1.7592x; 1.2849x over previous
//
#include <hip/hip_runtime.h>

#define D 128
#define NBSHIFT 10          // 1024 nodes per bucket
#define EPB 2048            // edges per k_bucket block

typedef __attribute__((ext_vector_type(8))) short bf16x8;
typedef __attribute__((ext_vector_type(4))) float floatx4;

__device__ __forceinline__ float bflo(unsigned int u){ return __uint_as_float(u << 16); }
__device__ __forceinline__ float bfhi(unsigned int u){ return __uint_as_float(u & 0xffff0000u); }
__device__ __forceinline__ unsigned int f2bfbits(float f){
    unsigned int x = __float_as_uint(f);
    return (x + 0x7fffu + ((x >> 16) & 1u)) >> 16;  // RNE, finite inputs
}

// ---- degree histogram over dst (self-loop added later as +1) ----
__global__ __launch_bounds__(256) void k_deg(const int* __restrict__ dst, int* __restrict__ deg, int E){
    int i = blockIdx.x * 256 + threadIdx.x;
    if (i < E) atomicAdd(&deg[dst[i]], 1);
}

__global__ __launch_bounds__(256) void k_dinv(const int* __restrict__ deg, float* __restrict__ dinv, int N){
    int i = blockIdx.x * 256 + threadIdx.x;
    if (i < N) dinv[i] = rsqrtf((float)deg[i] + 1.0f);  // +1 = self-loop; always > 0
}

// ======== device-wide exclusive scan of deg (3 small kernels) ========
__global__ __launch_bounds__(256) void k_part(const int* __restrict__ deg, int* __restrict__ bsum, int N){
    int b = blockIdx.x, t = threadIdx.x;
    int base = b * 2048 + t * 8;
    int s = 0;
#pragma unroll
    for (int j = 0; j < 8; ++j) s += (base + j < N) ? deg[base + j] : 0;
#pragma unroll
    for (int off = 32; off > 0; off >>= 1) s += __shfl_xor(s, off, 64);
    __shared__ int sm[4];
    if ((t & 63) == 0) sm[t >> 6] = s;
    __syncthreads();
    if (t == 0) bsum[b] = sm[0] + sm[1] + sm[2] + sm[3];
}

__global__ __launch_bounds__(256) void k_ssum(int* __restrict__ bsum, int nb, int* __restrict__ rowStartN){
    __shared__ int sm[256];
    int t = threadIdx.x;
    int C = (nb + 255) >> 8;
    int lo = t * C, hi = min(lo + C, nb);
    int s = 0;
    for (int i = lo; i < hi; ++i) s += bsum[i];
    sm[t] = s; __syncthreads();
    for (int off = 1; off < 256; off <<= 1){
        int x = (t >= off) ? sm[t - off] : 0;
        __syncthreads();
        sm[t] += x;
        __syncthreads();
    }
    int run = (t > 0) ? sm[t - 1] : 0;
    for (int i = lo; i < hi; ++i){ int v = bsum[i]; bsum[i] = run; run += v; }
    if (t == 255) *rowStartN = sm[255];
}

__global__ __launch_bounds__(256) void k_final(const int* __restrict__ deg, const int* __restrict__ bsum,
                                               int* __restrict__ rowStart, int N){
    int b = blockIdx.x, t = threadIdx.x;
    int base = b * 2048 + t * 8;
    int v[8]; int tot = 0;
#pragma unroll
    for (int j = 0; j < 8; ++j){ v[j] = (base + j < N) ? deg[base + j] : 0; tot += v[j]; }
    __shared__ int sm[256];
    sm[t] = tot; __syncthreads();
    for (int off = 1; off < 256; off <<= 1){
        int x = (t >= off) ? sm[t - off] : 0;
        __syncthreads();
        sm[t] += x;
        __syncthreads();
    }
    int run = ((t > 0) ? sm[t - 1] : 0) + bsum[b];
#pragma unroll
    for (int j = 0; j < 8; ++j){
        if (base + j < N){ rowStart[base + j] = run; run += v[j]; }
    }
}

// bucket cursors init: bcur[b] = rowStart[b<<NBSHIFT]
__global__ __launch_bounds__(256) void k_binit(const int* __restrict__ rowStart, int* __restrict__ bcur, int NBK){
    int t = blockIdx.x * 256 + threadIdx.x;
    if (t < NBK) bcur[t] = rowStart[t << NBSHIFT];
}

// ---- pass 1: LDS-staged partition of edges into dst-buckets (coalesced writes) ----
__global__ __launch_bounds__(256) void k_bucket(const int* __restrict__ src, const int* __restrict__ dst,
                                                int* __restrict__ bcur, uint2* __restrict__ edge2,
                                                int NBK, int E){
    __shared__ int hist[128], lstart[128], lcur[128], gbase[128];
    __shared__ uint2 stage[EPB];
    int t = threadIdx.x;
    int base = blockIdx.x * EPB;
    int tot = min(EPB, E - base);
    if (t < 128) hist[t] = 0;
    __syncthreads();

    uint2 ent[8]; int bk[8]; int cnt = 0;
#pragma unroll
    for (int j = 0; j < 8; ++j){
        int e = base + j * 256 + t;
        if (e < base + tot){
            unsigned s = (unsigned)src[e], d = (unsigned)dst[e];
            ent[cnt] = make_uint2(s, d);
            bk[cnt] = (int)(d >> NBSHIFT);
            atomicAdd(&hist[bk[cnt]], 1);
            ++cnt;
        }
    }
    __syncthreads();
    // inclusive scan of hist -> lstart
    if (t < 128) lstart[t] = hist[t];
    __syncthreads();
    for (int off = 1; off < 128; off <<= 1){
        int v = 0;
        if (t < 128 && t >= off) v = lstart[t - off];
        __syncthreads();
        if (t < 128) lstart[t] += v;
        __syncthreads();
    }
    // convert to exclusive; grab global bases
    if (t < 128){
        int ex = lstart[t] - hist[t];
        lstart[t] = ex;
        lcur[t] = ex;
        if (t < NBK && hist[t] > 0) gbase[t] = atomicAdd(&bcur[t], hist[t]);
    }
    __syncthreads();
    // place into staging grouped by bucket
    for (int j = 0; j < cnt; ++j){
        int pos = atomicAdd(&lcur[bk[j]], 1);
        stage[pos] = ent[j];
    }
    __syncthreads();
    // stream out: consecutive i within a bucket -> consecutive global positions
    for (int i = t; i < tot; i += 256){
        uint2 e2 = stage[i];
        int b = (int)(e2.y >> NBSHIFT);
        edge2[gbase[b] + (i - lstart[b])] = e2;
    }
}

// ---- pass 2: per-bucket CSR scatter; block-owned csr window, LDS cursors ----
__global__ __launch_bounds__(256) void k_csr(const uint2* __restrict__ edge2, const int* __restrict__ rowStart,
                                             int* __restrict__ csr, int N){
    __shared__ int cur[1 << NBSHIFT];
    int b = blockIdx.x, t = threadIdx.x;
    int nbase = b << NBSHIFT;
    int nend = min(N, nbase + (1 << NBSHIFT));
    int nn = nend - nbase;
    for (int i = t; i < nn; i += 256) cur[i] = rowStart[nbase + i];
    __syncthreads();
    int estart = rowStart[nbase], eend = rowStart[nend];
    for (int i = estart + t; i < eend; i += 256){
        uint2 e2 = edge2[i];
        int pos = atomicAdd(&cur[(int)e2.y - nbase], 1);
        csr[pos] = (int)e2.x;
    }
}

// ---- transpose + fp32->bf16 both weight matrices: Wt[n][k] = bf16(W[k][n]) ----
__global__ __launch_bounds__(256) void k_wtrans(const float* __restrict__ W1,
                                                const float* __restrict__ W2,
                                                unsigned short* __restrict__ Wt1,
                                                unsigned short* __restrict__ Wt2){
    int i = blockIdx.x * 256 + threadIdx.x;  // 0..32767
    const float* Ws; unsigned short* Wd; int j = i;
    if (i < 16384){ Ws = W1; Wd = Wt1; } else { Ws = W2; Wd = Wt2; j -= 16384; }
    int k = j >> 7, n = j & 127;
    Wd[n * 128 + k] = (unsigned short)f2bfbits(Ws[k * 128 + n]);
}

// ---- bf16 MFMA GEMM: H[N x 128] = bf16(A) @ bf16(W); H stored BF16 now ----
__global__ __launch_bounds__(256) void k_gemm(const float* __restrict__ A,
                                              const unsigned short* __restrict__ Wt,
                                              unsigned short* __restrict__ Hout, int Nrows){
    int wave = threadIdx.x >> 6, lane = threadIdx.x & 63;
    int m = lane & 15, quad = lane >> 4;
    int row0 = blockIdx.x * 64 + wave * 16;
    int arow = row0 + m;
    int arowc = arow < Nrows ? arow : Nrows - 1;  // clamp loads; stores guarded

    bf16x8 a[4];
    const float* Ap = A + (size_t)arowc * D + quad * 8;
#pragma unroll
    for (int kt = 0; kt < 4; ++kt){
        float4 v0 = *(const float4*)(Ap + kt * 32);
        float4 v1 = *(const float4*)(Ap + kt * 32 + 4);
        bf16x8 af;
        af[0] = (short)f2bfbits(v0.x); af[1] = (short)f2bfbits(v0.y);
        af[2] = (short)f2bfbits(v0.z); af[3] = (short)f2bfbits(v0.w);
        af[4] = (short)f2bfbits(v1.x); af[5] = (short)f2bfbits(v1.y);
        af[6] = (short)f2bfbits(v1.z); af[7] = (short)f2bfbits(v1.w);
        a[kt] = af;
    }

    floatx4 acc[8];
#pragma unroll
    for (int nt = 0; nt < 8; ++nt) acc[nt] = (floatx4){0.f, 0.f, 0.f, 0.f};

    const unsigned short* Bp = Wt + m * D + quad * 8;  // B frag: n = lane&15, k = quad*8+j
#pragma unroll
    for (int kt = 0; kt < 4; ++kt){
        bf16x8 bk[8];
#pragma unroll
        for (int nt = 0; nt < 8; ++nt) bk[nt] = *(const bf16x8*)(Bp + nt * 16 * D + kt * 32);
#pragma unroll
        for (int nt = 0; nt < 8; ++nt)
            acc[nt] = __builtin_amdgcn_mfma_f32_16x16x32_bf16(a[kt], bk[nt], acc[nt], 0, 0, 0);
    }
#pragma unroll
    for (int nt = 0; nt < 8; ++nt){
#pragma unroll
        for (int r = 0; r < 4; ++r){
            int rr = row0 + quad * 4 + r;
            if (rr < Nrows) Hout[(size_t)rr * D + nt * 16 + m] = (unsigned short)f2bfbits(acc[nt][r]);
        }
    }
}

// ---- fused gather-aggregate + bias + LayerNorm + ReLU ----
// one wave per node; 2 edges in flight (half-wave per edge); h is bf16 (8 B/lane/row)
__global__ __launch_bounds__(256) void k_agg(const unsigned short* __restrict__ h,
                                             const int* __restrict__ rowStart,
                                             const int* __restrict__ csr,
                                             const float* __restrict__ dinv,
                                             const float* __restrict__ bias,
                                             const float* __restrict__ gamma,
                                             const float* __restrict__ beta,
                                             float* __restrict__ out, int N){
    int node = blockIdx.x * 4 + (threadIdx.x >> 6);
    if (node >= N) return;  // wave-uniform exit
    int lane = threadIdx.x & 63;
    int half = lane >> 5, li = lane & 31;   // lane owns channels 4*li..4*li+3
    const uint2* hv = (const uint2*)h;      // 32 uint2 per row (4 bf16 each)

    float dv = dinv[node];
    float4 acc = {0.f, 0.f, 0.f, 0.f};
    if (half == 0){
        uint2 hs = hv[(size_t)node * 32 + li];
        float w0 = dv * dv;  // self-loop norm
        acc.x = bflo(hs.x) * w0; acc.y = bfhi(hs.x) * w0;
        acc.z = bflo(hs.y) * w0; acc.w = bfhi(hs.y) * w0;
    }

    int end = rowStart[node + 1];
    int e = rowStart[node] + half;
    int s_next = (e < end) ? csr[e] : 0;
    while (e < end){
        int s = s_next;
        int en = e + 2;
        if (en < end) s_next = csr[en];  // prefetch
        float ws = dinv[s] * dv;
        uint2 hs = hv[(size_t)s * 32 + li];
        acc.x = fmaf(bflo(hs.x), ws, acc.x);
        acc.y = fmaf(bfhi(hs.x), ws, acc.y);
        acc.z = fmaf(bflo(hs.y), ws, acc.z);
        acc.w = fmaf(bfhi(hs.y), ws, acc.w);
        e = en;
    }
    // combine the two half-wave partial sums
    acc.x += __shfl_xor(acc.x, 32, 64);
    acc.y += __shfl_xor(acc.y, 32, 64);
    acc.z += __shfl_xor(acc.z, 32, 64);
    acc.w += __shfl_xor(acc.w, 32, 64);

    float4 bb = ((const float4*)bias)[li];
    acc.x += bb.x; acc.y += bb.y; acc.z += bb.z; acc.w += bb.w;

    float s1 = acc.x + acc.y + acc.z + acc.w;
    float s2 = acc.x * acc.x + acc.y * acc.y + acc.z * acc.z + acc.w * acc.w;
#pragma unroll
    for (int off = 16; off > 0; off >>= 1){
        s1 += __shfl_xor(s1, off, 64);
        s2 += __shfl_xor(s2, off, 64);
    }
    float mu = s1 * (1.0f / 128.0f);
    float var = s2 * (1.0f / 128.0f) - mu * mu;
    float rstd = rsqrtf(var + 1e-5f);

    float4 gg = ((const float4*)gamma)[li];
    float4 be = ((const float4*)beta)[li];
    float4 o;
    o.x = fmaxf(fmaf((acc.x - mu) * rstd, gg.x, be.x), 0.0f);
    o.y = fmaxf(fmaf((acc.y - mu) * rstd, gg.y, be.y), 0.0f);
    o.z = fmaxf(fmaf((acc.z - mu) * rstd, gg.z, be.z), 0.0f);
    o.w = fmaxf(fmaf((acc.w - mu) * rstd, gg.w, be.w), 0.0f);
    if (half == 0) ((float4*)out)[(size_t)node * 32 + li] = o;
}

extern "C" void kernel_launch(void* const* d_in, const int* in_sizes, int n_in,
                              void* d_out, int out_size, void* d_ws, size_t ws_size,
                              hipStream_t stream){
    const float* x   = (const float*)d_in[0];
    const int*   ei  = (const int*)d_in[1];
    const float* W1  = (const float*)d_in[2];
    const float* b1  = (const float*)d_in[3];
    const float* g1  = (const float*)d_in[4];
    const float* be1 = (const float*)d_in[5];
    const float* W2  = (const float*)d_in[6];
    const float* b2  = (const float*)d_in[7];
    const float* g2  = (const float*)d_in[8];
    const float* be2 = (const float*)d_in[9];
    float* out = (float*)d_out;

    const int N = in_sizes[0] / D;
    const int E = in_sizes[1] / 2;
    const int* src = ei;
    const int* dst = ei + E;

    char* w = (char*)d_ws;
    size_t off = 0;
    auto alloc = [&](size_t bytes) -> char* {
        char* p = w + off;
        off = (off + bytes + 255) & ~(size_t)255;
        return p;
    };
    const int nchunk = (N + 2047) / 2048;
    const int NBK = (N + (1 << NBSHIFT) - 1) >> NBSHIFT;
    int*            deg      = (int*)alloc((size_t)N * 4);
    float*          dinv     = (float*)alloc((size_t)N * 4);
    int*            rowStart = (int*)alloc((size_t)(N + 1) * 4);
    int*            bsum     = (int*)alloc((size_t)nchunk * 4);
    int*            bcur     = (int*)alloc((size_t)NBK * 4);
    uint2*          edge2    = (uint2*)alloc((size_t)E * 8);
    int*            csr      = (int*)alloc((size_t)E * 4);
    unsigned short* wt1      = (unsigned short*)alloc(16384 * 2);
    unsigned short* wt2      = (unsigned short*)alloc(16384 * 2);
    unsigned short* h        = (unsigned short*)alloc((size_t)N * D * 2);
    float*          hpost    = out;  // reuse d_out as layer-1 activation buffer

    (void)hipMemsetAsync(deg, 0, (size_t)N * 4, stream);

    int gE = (E + 255) / 256;
    int gN = (N + 255) / 256;
    int gB = (E + EPB - 1) / EPB;
    int gG = (N + 63) / 64;
    int gA = (N + 3) / 4;

    k_deg   <<<gE, 256, 0, stream>>>(dst, deg, E);
    k_dinv  <<<gN, 256, 0, stream>>>(deg, dinv, N);
    k_part  <<<nchunk, 256, 0, stream>>>(deg, bsum, N);
    k_ssum  <<<1, 256, 0, stream>>>(bsum, nchunk, rowStart + N);
    k_final <<<nchunk, 256, 0, stream>>>(deg, bsum, rowStart, N);
    k_binit <<<1, 256, 0, stream>>>(rowStart, bcur, NBK);
    k_bucket<<<gB, 256, 0, stream>>>(src, dst, bcur, edge2, NBK, E);
    k_csr   <<<NBK, 256, 0, stream>>>(edge2, rowStart, csr, N);
    k_wtrans<<<128, 256, 0, stream>>>(W1, W2, wt1, wt2);

    // layer 1
    k_gemm<<<gG, 256, 0, stream>>>(x, wt1, h, N);
    k_agg <<<gA, 256, 0, stream>>>(h, rowStart, csr, dinv, b1, g1, be1, hpost, N);
    // layer 2
    k_gemm<<<gG, 256, 0, stream>>>(hpost, wt2, h, N);
    k_agg <<<gA, 256, 0, stream>>>(h, rowStart, csr, dinv, b2, g2, be2, out, N);
}

// Round 5
// 481.893 us; speedup vs baseline: 1.7825x; 1.0133x over previous
//
#include <hip/hip_runtime.h>

#define D 128
#define NBSHIFT 10          // 1024 nodes per bucket
#define EPB 2048            // edges per k_bucket block

typedef __attribute__((ext_vector_type(8))) short bf16x8;
typedef __attribute__((ext_vector_type(4))) float floatx4;

__device__ __forceinline__ float bflo(unsigned int u){ return __uint_as_float(u << 16); }
__device__ __forceinline__ float bfhi(unsigned int u){ return __uint_as_float(u & 0xffff0000u); }
__device__ __forceinline__ unsigned int f2bfbits(float f){
    unsigned int x = __float_as_uint(f);
    return (x + 0x7fffu + ((x >> 16) & 1u)) >> 16;  // RNE, finite inputs
}

// ---- degree histogram over dst ----
__global__ __launch_bounds__(256) void k_deg(const int* __restrict__ dst, int* __restrict__ deg, int E){
    int i = blockIdx.x * 256 + threadIdx.x;
    if (i < E) atomicAdd(&deg[dst[i]], 1);
}

__global__ __launch_bounds__(256) void k_dinv(const int* __restrict__ deg, float* __restrict__ dinv, int N){
    int i = blockIdx.x * 256 + threadIdx.x;
    if (i < N) dinv[i] = rsqrtf((float)deg[i] + 1.0f);  // +1 = self-loop
}

// ======== device-wide exclusive scan of deg ========
__global__ __launch_bounds__(256) void k_part(const int* __restrict__ deg, int* __restrict__ bsum, int N){
    int b = blockIdx.x, t = threadIdx.x;
    int base = b * 2048 + t * 8;
    int s = 0;
#pragma unroll
    for (int j = 0; j < 8; ++j) s += (base + j < N) ? deg[base + j] : 0;
#pragma unroll
    for (int off = 32; off > 0; off >>= 1) s += __shfl_xor(s, off, 64);
    __shared__ int sm[4];
    if ((t & 63) == 0) sm[t >> 6] = s;
    __syncthreads();
    if (t == 0) bsum[b] = sm[0] + sm[1] + sm[2] + sm[3];
}

__global__ __launch_bounds__(256) void k_ssum(int* __restrict__ bsum, int nb, int* __restrict__ rowStartN){
    __shared__ int sm[256];
    int t = threadIdx.x;
    int C = (nb + 255) >> 8;
    int lo = t * C, hi = min(lo + C, nb);
    int s = 0;
    for (int i = lo; i < hi; ++i) s += bsum[i];
    sm[t] = s; __syncthreads();
    for (int off = 1; off < 256; off <<= 1){
        int x = (t >= off) ? sm[t - off] : 0;
        __syncthreads();
        sm[t] += x;
        __syncthreads();
    }
    int run = (t > 0) ? sm[t - 1] : 0;
    for (int i = lo; i < hi; ++i){ int v = bsum[i]; bsum[i] = run; run += v; }
    if (t == 255) *rowStartN = sm[255];
}

__global__ __launch_bounds__(256) void k_final(const int* __restrict__ deg, const int* __restrict__ bsum,
                                               int* __restrict__ rowStart, int N){
    int b = blockIdx.x, t = threadIdx.x;
    int base = b * 2048 + t * 8;
    int v[8]; int tot = 0;
#pragma unroll
    for (int j = 0; j < 8; ++j){ v[j] = (base + j < N) ? deg[base + j] : 0; tot += v[j]; }
    __shared__ int sm[256];
    sm[t] = tot; __syncthreads();
    for (int off = 1; off < 256; off <<= 1){
        int x = (t >= off) ? sm[t - off] : 0;
        __syncthreads();
        sm[t] += x;
        __syncthreads();
    }
    int run = ((t > 0) ? sm[t - 1] : 0) + bsum[b];
#pragma unroll
    for (int j = 0; j < 8; ++j){
        if (base + j < N){ rowStart[base + j] = run; run += v[j]; }
    }
}

__global__ __launch_bounds__(256) void k_binit(const int* __restrict__ rowStart, int* __restrict__ bcur, int NBK){
    int t = blockIdx.x * 256 + threadIdx.x;
    if (t < NBK) bcur[t] = rowStart[t << NBSHIFT];
}

// ---- pass 1: LDS-staged partition of edges into dst-buckets ----
__global__ __launch_bounds__(256) void k_bucket(const int* __restrict__ src, const int* __restrict__ dst,
                                                int* __restrict__ bcur, uint2* __restrict__ edge2,
                                                int NBK, int E){
    __shared__ int hist[128], lstart[128], lcur[128], gbase[128];
    __shared__ uint2 stage[EPB];
    int t = threadIdx.x;
    int base = blockIdx.x * EPB;
    int tot = min(EPB, E - base);
    if (t < 128) hist[t] = 0;
    __syncthreads();

    uint2 ent[8]; int bk[8]; int cnt = 0;
#pragma unroll
    for (int j = 0; j < 8; ++j){
        int e = base + j * 256 + t;
        if (e < base + tot){
            unsigned s = (unsigned)src[e], d = (unsigned)dst[e];
            ent[cnt] = make_uint2(s, d);
            bk[cnt] = (int)(d >> NBSHIFT);
            atomicAdd(&hist[bk[cnt]], 1);
            ++cnt;
        }
    }
    __syncthreads();
    if (t < 128) lstart[t] = hist[t];
    __syncthreads();
    for (int off = 1; off < 128; off <<= 1){
        int v = 0;
        if (t < 128 && t >= off) v = lstart[t - off];
        __syncthreads();
        if (t < 128) lstart[t] += v;
        __syncthreads();
    }
    if (t < 128){
        int ex = lstart[t] - hist[t];
        lstart[t] = ex;
        lcur[t] = ex;
        if (t < NBK && hist[t] > 0) gbase[t] = atomicAdd(&bcur[t], hist[t]);
    }
    __syncthreads();
    for (int j = 0; j < cnt; ++j){
        int pos = atomicAdd(&lcur[bk[j]], 1);
        stage[pos] = ent[j];
    }
    __syncthreads();
    for (int i = t; i < tot; i += 256){
        uint2 e2 = stage[i];
        int b = (int)(e2.y >> NBSHIFT);
        edge2[gbase[b] + (i - lstart[b])] = e2;
    }
}

// ---- pass 2: per-bucket CSR scatter ----
__global__ __launch_bounds__(256) void k_csr(const uint2* __restrict__ edge2, const int* __restrict__ rowStart,
                                             int* __restrict__ csr, int N){
    __shared__ int cur[1 << NBSHIFT];
    int b = blockIdx.x, t = threadIdx.x;
    int nbase = b << NBSHIFT;
    int nend = min(N, nbase + (1 << NBSHIFT));
    int nn = nend - nbase;
    for (int i = t; i < nn; i += 256) cur[i] = rowStart[nbase + i];
    __syncthreads();
    int estart = rowStart[nbase], eend = rowStart[nend];
    for (int i = estart + t; i < eend; i += 256){
        uint2 e2 = edge2[i];
        int pos = atomicAdd(&cur[(int)e2.y - nbase], 1);
        csr[pos] = (int)e2.x;
    }
}

// ---- transpose + fp32->bf16 weights ----
__global__ __launch_bounds__(256) void k_wtrans(const float* __restrict__ W1,
                                                const float* __restrict__ W2,
                                                unsigned short* __restrict__ Wt1,
                                                unsigned short* __restrict__ Wt2){
    int i = blockIdx.x * 256 + threadIdx.x;
    const float* Ws; unsigned short* Wd; int j = i;
    if (i < 16384){ Ws = W1; Wd = Wt1; } else { Ws = W2; Wd = Wt2; j -= 16384; }
    int k = j >> 7, n = j & 127;
    Wd[n * 128 + k] = (unsigned short)f2bfbits(Ws[k * 128 + n]);
}

// ---- bf16 MFMA GEMM, templated on A dtype; H stored bf16 ----
template<bool A_BF16>
__global__ __launch_bounds__(256) void k_gemm(const void* __restrict__ Av,
                                              const unsigned short* __restrict__ Wt,
                                              unsigned short* __restrict__ Hout, int Nrows){
    int wave = threadIdx.x >> 6, lane = threadIdx.x & 63;
    int m = lane & 15, quad = lane >> 4;
    int row0 = blockIdx.x * 64 + wave * 16;
    int arow = row0 + m;
    int arowc = arow < Nrows ? arow : Nrows - 1;

    bf16x8 a[4];
    if (A_BF16){
        const unsigned short* Ap = (const unsigned short*)Av + (size_t)arowc * D + quad * 8;
#pragma unroll
        for (int kt = 0; kt < 4; ++kt) a[kt] = *(const bf16x8*)(Ap + kt * 32);
    } else {
        const float* Ap = (const float*)Av + (size_t)arowc * D + quad * 8;
#pragma unroll
        for (int kt = 0; kt < 4; ++kt){
            float4 v0 = *(const float4*)(Ap + kt * 32);
            float4 v1 = *(const float4*)(Ap + kt * 32 + 4);
            bf16x8 af;
            af[0] = (short)f2bfbits(v0.x); af[1] = (short)f2bfbits(v0.y);
            af[2] = (short)f2bfbits(v0.z); af[3] = (short)f2bfbits(v0.w);
            af[4] = (short)f2bfbits(v1.x); af[5] = (short)f2bfbits(v1.y);
            af[6] = (short)f2bfbits(v1.z); af[7] = (short)f2bfbits(v1.w);
            a[kt] = af;
        }
    }

    floatx4 acc[8];
#pragma unroll
    for (int nt = 0; nt < 8; ++nt) acc[nt] = (floatx4){0.f, 0.f, 0.f, 0.f};

    const unsigned short* Bp = Wt + m * D + quad * 8;
#pragma unroll
    for (int kt = 0; kt < 4; ++kt){
        bf16x8 bk[8];
#pragma unroll
        for (int nt = 0; nt < 8; ++nt) bk[nt] = *(const bf16x8*)(Bp + nt * 16 * D + kt * 32);
#pragma unroll
        for (int nt = 0; nt < 8; ++nt)
            acc[nt] = __builtin_amdgcn_mfma_f32_16x16x32_bf16(a[kt], bk[nt], acc[nt], 0, 0, 0);
    }
#pragma unroll
    for (int nt = 0; nt < 8; ++nt){
#pragma unroll
        for (int r = 0; r < 4; ++r){
            int rr = row0 + quad * 4 + r;
            if (rr < Nrows) Hout[(size_t)rr * D + nt * 16 + m] = (unsigned short)f2bfbits(acc[nt][r]);
        }
    }
}

// ---- fused gather-aggregate + bias + LayerNorm + ReLU ----
// one wave/node; half-wave per contiguous edge sub-range; 4 edges batched per iter.
template<bool OUT_BF16>
__global__ __launch_bounds__(256) void k_agg(const unsigned short* __restrict__ h,
                                             const int* __restrict__ rowStart,
                                             const int* __restrict__ csr,
                                             const float* __restrict__ dinv,
                                             const float* __restrict__ bias,
                                             const float* __restrict__ gamma,
                                             const float* __restrict__ beta,
                                             void* __restrict__ outv, int N){
    int node = blockIdx.x * 4 + (threadIdx.x >> 6);
    if (node >= N) return;
    int lane = threadIdx.x & 63;
    int half = lane >> 5, li = lane & 31;   // lane owns channels 4*li..4*li+3
    const uint2* hv = (const uint2*)h;

    float dv = dinv[node];
    float4 acc = {0.f, 0.f, 0.f, 0.f};
    if (half == 0){
        uint2 hs = hv[(size_t)node * 32 + li];
        float w0 = dv * dv;
        acc.x = bflo(hs.x) * w0; acc.y = bfhi(hs.x) * w0;
        acc.z = bflo(hs.y) * w0; acc.w = bfhi(hs.y) * w0;
    }

    int start = rowStart[node], end = rowStart[node + 1];
    int mid = start + ((end - start + 1) >> 1);
    int i    = half ? mid : start;
    int iend = half ? end : mid;

    // 4-edge batch: issue all gathers before consuming (MLP)
    for (; i + 4 <= iend; i += 4){
        int s0 = csr[i], s1 = csr[i + 1], s2 = csr[i + 2], s3 = csr[i + 3];
        uint2 h0 = hv[(size_t)s0 * 32 + li];
        uint2 h1 = hv[(size_t)s1 * 32 + li];
        uint2 h2 = hv[(size_t)s2 * 32 + li];
        uint2 h3 = hv[(size_t)s3 * 32 + li];
        float w0 = dinv[s0] * dv, w1 = dinv[s1] * dv, w2 = dinv[s2] * dv, w3 = dinv[s3] * dv;
        acc.x = fmaf(bflo(h0.x), w0, acc.x); acc.y = fmaf(bfhi(h0.x), w0, acc.y);
        acc.z = fmaf(bflo(h0.y), w0, acc.z); acc.w = fmaf(bfhi(h0.y), w0, acc.w);
        acc.x = fmaf(bflo(h1.x), w1, acc.x); acc.y = fmaf(bfhi(h1.x), w1, acc.y);
        acc.z = fmaf(bflo(h1.y), w1, acc.z); acc.w = fmaf(bfhi(h1.y), w1, acc.w);
        acc.x = fmaf(bflo(h2.x), w2, acc.x); acc.y = fmaf(bfhi(h2.x), w2, acc.y);
        acc.z = fmaf(bflo(h2.y), w2, acc.z); acc.w = fmaf(bfhi(h2.y), w2, acc.w);
        acc.x = fmaf(bflo(h3.x), w3, acc.x); acc.y = fmaf(bfhi(h3.x), w3, acc.y);
        acc.z = fmaf(bflo(h3.y), w3, acc.z); acc.w = fmaf(bfhi(h3.y), w3, acc.w);
    }
    for (; i < iend; ++i){
        int s = csr[i];
        float ws = dinv[s] * dv;
        uint2 hs = hv[(size_t)s * 32 + li];
        acc.x = fmaf(bflo(hs.x), ws, acc.x); acc.y = fmaf(bfhi(hs.x), ws, acc.y);
        acc.z = fmaf(bflo(hs.y), ws, acc.z); acc.w = fmaf(bfhi(hs.y), ws, acc.w);
    }

    acc.x += __shfl_xor(acc.x, 32, 64);
    acc.y += __shfl_xor(acc.y, 32, 64);
    acc.z += __shfl_xor(acc.z, 32, 64);
    acc.w += __shfl_xor(acc.w, 32, 64);

    float4 bb = ((const float4*)bias)[li];
    acc.x += bb.x; acc.y += bb.y; acc.z += bb.z; acc.w += bb.w;

    float s1 = acc.x + acc.y + acc.z + acc.w;
    float s2 = acc.x * acc.x + acc.y * acc.y + acc.z * acc.z + acc.w * acc.w;
#pragma unroll
    for (int off = 16; off > 0; off >>= 1){
        s1 += __shfl_xor(s1, off, 64);
        s2 += __shfl_xor(s2, off, 64);
    }
    float mu = s1 * (1.0f / 128.0f);
    float var = s2 * (1.0f / 128.0f) - mu * mu;
    float rstd = rsqrtf(var + 1e-5f);

    float4 gg = ((const float4*)gamma)[li];
    float4 be = ((const float4*)beta)[li];
    float ox = fmaxf(fmaf((acc.x - mu) * rstd, gg.x, be.x), 0.0f);
    float oy = fmaxf(fmaf((acc.y - mu) * rstd, gg.y, be.y), 0.0f);
    float oz = fmaxf(fmaf((acc.z - mu) * rstd, gg.z, be.z), 0.0f);
    float ow = fmaxf(fmaf((acc.w - mu) * rstd, gg.w, be.w), 0.0f);
    if (half == 0){
        if (OUT_BF16){
            uint2 o;
            o.x = f2bfbits(ox) | (f2bfbits(oy) << 16);
            o.y = f2bfbits(oz) | (f2bfbits(ow) << 16);
            ((uint2*)outv)[(size_t)node * 32 + li] = o;
        } else {
            float4 o; o.x = ox; o.y = oy; o.z = oz; o.w = ow;
            ((float4*)outv)[(size_t)node * 32 + li] = o;
        }
    }
}

extern "C" void kernel_launch(void* const* d_in, const int* in_sizes, int n_in,
                              void* d_out, int out_size, void* d_ws, size_t ws_size,
                              hipStream_t stream){
    const float* x   = (const float*)d_in[0];
    const int*   ei  = (const int*)d_in[1];
    const float* W1  = (const float*)d_in[2];
    const float* b1  = (const float*)d_in[3];
    const float* g1  = (const float*)d_in[4];
    const float* be1 = (const float*)d_in[5];
    const float* W2  = (const float*)d_in[6];
    const float* b2  = (const float*)d_in[7];
    const float* g2  = (const float*)d_in[8];
    const float* be2 = (const float*)d_in[9];
    float* out = (float*)d_out;

    const int N = in_sizes[0] / D;
    const int E = in_sizes[1] / 2;
    const int* src = ei;
    const int* dst = ei + E;

    char* w = (char*)d_ws;
    size_t off = 0;
    auto alloc = [&](size_t bytes) -> char* {
        char* p = w + off;
        off = (off + bytes + 255) & ~(size_t)255;
        return p;
    };
    const int nchunk = (N + 2047) / 2048;
    const int NBK = (N + (1 << NBSHIFT) - 1) >> NBSHIFT;
    int*            deg      = (int*)alloc((size_t)N * 4);
    float*          dinv     = (float*)alloc((size_t)N * 4);
    int*            rowStart = (int*)alloc((size_t)(N + 1) * 4);
    int*            bsum     = (int*)alloc((size_t)nchunk * 4);
    int*            bcur     = (int*)alloc((size_t)NBK * 4);
    uint2*          edge2    = (uint2*)alloc((size_t)E * 8);
    int*            csr      = (int*)alloc((size_t)E * 4);
    unsigned short* wt1      = (unsigned short*)alloc(16384 * 2);
    unsigned short* wt2      = (unsigned short*)alloc(16384 * 2);
    unsigned short* h        = (unsigned short*)alloc((size_t)N * D * 2);
    size_t off_before_mid = off;
    unsigned short* hmid     = (unsigned short*)alloc((size_t)N * D * 2);
    bool midBf16 = (off <= ws_size);
    if (!midBf16) off = off_before_mid;  // fall back: fp32 mid in d_out

    (void)hipMemsetAsync(deg, 0, (size_t)N * 4, stream);

    int gE = (E + 255) / 256;
    int gN = (N + 255) / 256;
    int gB = (E + EPB - 1) / EPB;
    int gG = (N + 63) / 64;
    int gA = (N + 3) / 4;

    k_deg   <<<gE, 256, 0, stream>>>(dst, deg, E);
    k_dinv  <<<gN, 256, 0, stream>>>(deg, dinv, N);
    k_part  <<<nchunk, 256, 0, stream>>>(deg, bsum, N);
    k_ssum  <<<1, 256, 0, stream>>>(bsum, nchunk, rowStart + N);
    k_final <<<nchunk, 256, 0, stream>>>(deg, bsum, rowStart, N);
    k_binit <<<1, 256, 0, stream>>>(rowStart, bcur, NBK);
    k_bucket<<<gB, 256, 0, stream>>>(src, dst, bcur, edge2, NBK, E);
    k_csr   <<<NBK, 256, 0, stream>>>(edge2, rowStart, csr, N);
    k_wtrans<<<128, 256, 0, stream>>>(W1, W2, wt1, wt2);

    // layer 1
    k_gemm<false><<<gG, 256, 0, stream>>>(x, wt1, h, N);
    if (midBf16){
        k_agg<true> <<<gA, 256, 0, stream>>>(h, rowStart, csr, dinv, b1, g1, be1, hmid, N);
        k_gemm<true><<<gG, 256, 0, stream>>>(hmid, wt2, h, N);
    } else {
        k_agg<false><<<gA, 256, 0, stream>>>(h, rowStart, csr, dinv, b1, g1, be1, out, N);
        k_gemm<false><<<gG, 256, 0, stream>>>(out, wt2, h, N);
    }
    // layer 2
    k_agg<false><<<gA, 256, 0, stream>>>(h, rowStart, csr, dinv, b2, g2, be2, out, N);
}

// Round 6
// 475.434 us; speedup vs baseline: 1.8067x; 1.0136x over previous
//
#include <hip/hip_runtime.h>

#define D 128
#define NBSHIFT 10          // 1024 nodes per bucket
#define EPB 2048            // edges per k_bucket block

typedef __attribute__((ext_vector_type(8))) short bf16x8;
typedef __attribute__((ext_vector_type(4))) float floatx4;

__device__ __forceinline__ float bflo(unsigned int u){ return __uint_as_float(u << 16); }
__device__ __forceinline__ float bfhi(unsigned int u){ return __uint_as_float(u & 0xffff0000u); }
__device__ __forceinline__ unsigned int f2bfbits(float f){
    unsigned int x = __float_as_uint(f);
    return (x + 0x7fffu + ((x >> 16) & 1u)) >> 16;  // RNE, finite inputs
}

// ---- degree histogram over dst ----
__global__ __launch_bounds__(256) void k_deg(const int* __restrict__ dst, int* __restrict__ deg, int E){
    int i = blockIdx.x * 256 + threadIdx.x;
    if (i < E) atomicAdd(&deg[dst[i]], 1);
}

// ======== device-wide exclusive scan of deg ========
__global__ __launch_bounds__(256) void k_part(const int* __restrict__ deg, int* __restrict__ bsum, int N){
    int b = blockIdx.x, t = threadIdx.x;
    int base = b * 2048 + t * 8;
    int s = 0;
#pragma unroll
    for (int j = 0; j < 8; ++j) s += (base + j < N) ? deg[base + j] : 0;
#pragma unroll
    for (int off = 32; off > 0; off >>= 1) s += __shfl_xor(s, off, 64);
    __shared__ int sm[4];
    if ((t & 63) == 0) sm[t >> 6] = s;
    __syncthreads();
    if (t == 0) bsum[b] = sm[0] + sm[1] + sm[2] + sm[3];
}

__global__ __launch_bounds__(256) void k_ssum(int* __restrict__ bsum, int nb, int* __restrict__ rowStartN){
    __shared__ int sm[256];
    int t = threadIdx.x;
    int C = (nb + 255) >> 8;
    int lo = t * C, hi = min(lo + C, nb);
    int s = 0;
    for (int i = lo; i < hi; ++i) s += bsum[i];
    sm[t] = s; __syncthreads();
    for (int off = 1; off < 256; off <<= 1){
        int x = (t >= off) ? sm[t - off] : 0;
        __syncthreads();
        sm[t] += x;
        __syncthreads();
    }
    int run = (t > 0) ? sm[t - 1] : 0;
    for (int i = lo; i < hi; ++i){ int v = bsum[i]; bsum[i] = run; run += v; }
    if (t == 255) *rowStartN = sm[255];
}

// rowStart + dinv + bucket-cursor init, fused
__global__ __launch_bounds__(256) void k_final(const int* __restrict__ deg, const int* __restrict__ bsum,
                                               int* __restrict__ rowStart, float* __restrict__ dinv,
                                               int* __restrict__ bcur, int N){
    int b = blockIdx.x, t = threadIdx.x;
    int base = b * 2048 + t * 8;
    int v[8]; int tot = 0;
#pragma unroll
    for (int j = 0; j < 8; ++j){ v[j] = (base + j < N) ? deg[base + j] : 0; tot += v[j]; }
    __shared__ int sm[256];
    sm[t] = tot; __syncthreads();
    for (int off = 1; off < 256; off <<= 1){
        int x = (t >= off) ? sm[t - off] : 0;
        __syncthreads();
        sm[t] += x;
        __syncthreads();
    }
    int run = ((t > 0) ? sm[t - 1] : 0) + bsum[b];
#pragma unroll
    for (int j = 0; j < 8; ++j){
        int i = base + j;
        if (i < N){
            rowStart[i] = run;
            dinv[i] = rsqrtf((float)v[j] + 1.0f);           // +1 = self-loop
            if ((i & ((1 << NBSHIFT) - 1)) == 0) bcur[i >> NBSHIFT] = run;
            run += v[j];
        }
    }
}

// ---- pass 1: LDS-staged partition of edges into dst-buckets ----
__global__ __launch_bounds__(256) void k_bucket(const int* __restrict__ src, const int* __restrict__ dst,
                                                int* __restrict__ bcur, uint2* __restrict__ edge2,
                                                int NBK, int E){
    __shared__ int hist[128], lstart[128], lcur[128], gbase[128];
    __shared__ uint2 stage[EPB];
    int t = threadIdx.x;
    int base = blockIdx.x * EPB;
    int tot = min(EPB, E - base);
    if (t < 128) hist[t] = 0;
    __syncthreads();

    uint2 ent[8]; int bk[8]; int cnt = 0;
#pragma unroll
    for (int j = 0; j < 8; ++j){
        int e = base + j * 256 + t;
        if (e < base + tot){
            unsigned s = (unsigned)src[e], d = (unsigned)dst[e];
            ent[cnt] = make_uint2(s, d);
            bk[cnt] = (int)(d >> NBSHIFT);
            atomicAdd(&hist[bk[cnt]], 1);
            ++cnt;
        }
    }
    __syncthreads();
    if (t < 128) lstart[t] = hist[t];
    __syncthreads();
    for (int off = 1; off < 128; off <<= 1){
        int v = 0;
        if (t < 128 && t >= off) v = lstart[t - off];
        __syncthreads();
        if (t < 128) lstart[t] += v;
        __syncthreads();
    }
    if (t < 128){
        int ex = lstart[t] - hist[t];
        lstart[t] = ex;
        lcur[t] = ex;
        if (t < NBK && hist[t] > 0) gbase[t] = atomicAdd(&bcur[t], hist[t]);
    }
    __syncthreads();
    for (int j = 0; j < cnt; ++j){
        int pos = atomicAdd(&lcur[bk[j]], 1);
        stage[pos] = ent[j];
    }
    __syncthreads();
    for (int i = t; i < tot; i += 256){
        uint2 e2 = stage[i];
        int b = (int)(e2.y >> NBSHIFT);
        edge2[gbase[b] + (i - lstart[b])] = e2;
    }
}

// ---- pass 2: per-bucket CSR scatter ----
__global__ __launch_bounds__(256) void k_csr(const uint2* __restrict__ edge2, const int* __restrict__ rowStart,
                                             int* __restrict__ csr, int N){
    __shared__ int cur[1 << NBSHIFT];
    int b = blockIdx.x, t = threadIdx.x;
    int nbase = b << NBSHIFT;
    int nend = min(N, nbase + (1 << NBSHIFT));
    int nn = nend - nbase;
    for (int i = t; i < nn; i += 256) cur[i] = rowStart[nbase + i];
    __syncthreads();
    int estart = rowStart[nbase], eend = rowStart[nend];
    for (int i = estart + t; i < eend; i += 256){
        uint2 e2 = edge2[i];
        int pos = atomicAdd(&cur[(int)e2.y - nbase], 1);
        csr[pos] = (int)e2.x;
    }
}

// ---- transpose + fp32->bf16 weights ----
__global__ __launch_bounds__(256) void k_wtrans(const float* __restrict__ W1,
                                                const float* __restrict__ W2,
                                                unsigned short* __restrict__ Wt1,
                                                unsigned short* __restrict__ Wt2){
    int i = blockIdx.x * 256 + threadIdx.x;
    const float* Ws; unsigned short* Wd; int j = i;
    if (i < 16384){ Ws = W1; Wd = Wt1; } else { Ws = W2; Wd = Wt2; j -= 16384; }
    int k = j >> 7, n = j & 127;
    Wd[n * 128 + k] = (unsigned short)f2bfbits(Ws[k * 128 + n]);
}

// ---- bf16 MFMA GEMM, templated on A dtype; H stored bf16 ----
template<bool A_BF16>
__global__ __launch_bounds__(256) void k_gemm(const void* __restrict__ Av,
                                              const unsigned short* __restrict__ Wt,
                                              unsigned short* __restrict__ Hout, int Nrows){
    int wave = threadIdx.x >> 6, lane = threadIdx.x & 63;
    int m = lane & 15, quad = lane >> 4;
    int row0 = blockIdx.x * 64 + wave * 16;
    int arow = row0 + m;
    int arowc = arow < Nrows ? arow : Nrows - 1;

    bf16x8 a[4];
    if (A_BF16){
        const unsigned short* Ap = (const unsigned short*)Av + (size_t)arowc * D + quad * 8;
#pragma unroll
        for (int kt = 0; kt < 4; ++kt) a[kt] = *(const bf16x8*)(Ap + kt * 32);
    } else {
        const float* Ap = (const float*)Av + (size_t)arowc * D + quad * 8;
#pragma unroll
        for (int kt = 0; kt < 4; ++kt){
            float4 v0 = *(const float4*)(Ap + kt * 32);
            float4 v1 = *(const float4*)(Ap + kt * 32 + 4);
            bf16x8 af;
            af[0] = (short)f2bfbits(v0.x); af[1] = (short)f2bfbits(v0.y);
            af[2] = (short)f2bfbits(v0.z); af[3] = (short)f2bfbits(v0.w);
            af[4] = (short)f2bfbits(v1.x); af[5] = (short)f2bfbits(v1.y);
            af[6] = (short)f2bfbits(v1.z); af[7] = (short)f2bfbits(v1.w);
            a[kt] = af;
        }
    }

    floatx4 acc[8];
#pragma unroll
    for (int nt = 0; nt < 8; ++nt) acc[nt] = (floatx4){0.f, 0.f, 0.f, 0.f};

    const unsigned short* Bp = Wt + m * D + quad * 8;
#pragma unroll
    for (int kt = 0; kt < 4; ++kt){
        bf16x8 bk[8];
#pragma unroll
        for (int nt = 0; nt < 8; ++nt) bk[nt] = *(const bf16x8*)(Bp + nt * 16 * D + kt * 32);
#pragma unroll
        for (int nt = 0; nt < 8; ++nt)
            acc[nt] = __builtin_amdgcn_mfma_f32_16x16x32_bf16(a[kt], bk[nt], acc[nt], 0, 0, 0);
    }
#pragma unroll
    for (int nt = 0; nt < 8; ++nt){
#pragma unroll
        for (int r = 0; r < 4; ++r){
            int rr = row0 + quad * 4 + r;
            if (rr < Nrows) Hout[(size_t)rr * D + nt * 16 + m] = (unsigned short)f2bfbits(acc[nt][r]);
        }
    }
}

// ---- fused gather-aggregate + bias + LayerNorm + ReLU ----
// OUT_BF16: bf16 (mid-layer). else: fp32 nontemporal (final output, never re-read).
template<bool OUT_BF16>
__global__ __launch_bounds__(256) void k_agg(const unsigned short* __restrict__ h,
                                             const int* __restrict__ rowStart,
                                             const int* __restrict__ csr,
                                             const float* __restrict__ dinv,
                                             const float* __restrict__ bias,
                                             const float* __restrict__ gamma,
                                             const float* __restrict__ beta,
                                             void* __restrict__ outv, int N){
    int node = blockIdx.x * 4 + (threadIdx.x >> 6);
    if (node >= N) return;
    int lane = threadIdx.x & 63;
    int half = lane >> 5, li = lane & 31;   // lane owns channels 4*li..4*li+3
    const uint2* hv = (const uint2*)h;

    float dv = dinv[node];
    float4 acc = {0.f, 0.f, 0.f, 0.f};
    if (half == 0){
        uint2 hs = hv[(size_t)node * 32 + li];
        float w0 = dv * dv;
        acc.x = bflo(hs.x) * w0; acc.y = bfhi(hs.x) * w0;
        acc.z = bflo(hs.y) * w0; acc.w = bfhi(hs.y) * w0;
    }

    int start = rowStart[node], end = rowStart[node + 1];
    int mid = start + ((end - start + 1) >> 1);
    int i    = half ? mid : start;
    int iend = half ? end : mid;

    for (; i + 4 <= iend; i += 4){
        int s0 = csr[i], s1 = csr[i + 1], s2 = csr[i + 2], s3 = csr[i + 3];
        uint2 h0 = hv[(size_t)s0 * 32 + li];
        uint2 h1 = hv[(size_t)s1 * 32 + li];
        uint2 h2 = hv[(size_t)s2 * 32 + li];
        uint2 h3 = hv[(size_t)s3 * 32 + li];
        float w0 = dinv[s0] * dv, w1 = dinv[s1] * dv, w2 = dinv[s2] * dv, w3 = dinv[s3] * dv;
        acc.x = fmaf(bflo(h0.x), w0, acc.x); acc.y = fmaf(bfhi(h0.x), w0, acc.y);
        acc.z = fmaf(bflo(h0.y), w0, acc.z); acc.w = fmaf(bfhi(h0.y), w0, acc.w);
        acc.x = fmaf(bflo(h1.x), w1, acc.x); acc.y = fmaf(bfhi(h1.x), w1, acc.y);
        acc.z = fmaf(bflo(h1.y), w1, acc.z); acc.w = fmaf(bfhi(h1.y), w1, acc.w);
        acc.x = fmaf(bflo(h2.x), w2, acc.x); acc.y = fmaf(bfhi(h2.x), w2, acc.y);
        acc.z = fmaf(bflo(h2.y), w2, acc.z); acc.w = fmaf(bfhi(h2.y), w2, acc.w);
        acc.x = fmaf(bflo(h3.x), w3, acc.x); acc.y = fmaf(bfhi(h3.x), w3, acc.y);
        acc.z = fmaf(bflo(h3.y), w3, acc.z); acc.w = fmaf(bfhi(h3.y), w3, acc.w);
    }
    for (; i < iend; ++i){
        int s = csr[i];
        float ws = dinv[s] * dv;
        uint2 hs = hv[(size_t)s * 32 + li];
        acc.x = fmaf(bflo(hs.x), ws, acc.x); acc.y = fmaf(bfhi(hs.x), ws, acc.y);
        acc.z = fmaf(bflo(hs.y), ws, acc.z); acc.w = fmaf(bfhi(hs.y), ws, acc.w);
    }

    acc.x += __shfl_xor(acc.x, 32, 64);
    acc.y += __shfl_xor(acc.y, 32, 64);
    acc.z += __shfl_xor(acc.z, 32, 64);
    acc.w += __shfl_xor(acc.w, 32, 64);

    float4 bb = ((const float4*)bias)[li];
    acc.x += bb.x; acc.y += bb.y; acc.z += bb.z; acc.w += bb.w;

    float s1 = acc.x + acc.y + acc.z + acc.w;
    float s2 = acc.x * acc.x + acc.y * acc.y + acc.z * acc.z + acc.w * acc.w;
#pragma unroll
    for (int off = 16; off > 0; off >>= 1){
        s1 += __shfl_xor(s1, off, 64);
        s2 += __shfl_xor(s2, off, 64);
    }
    float mu = s1 * (1.0f / 128.0f);
    float var = s2 * (1.0f / 128.0f) - mu * mu;
    float rstd = rsqrtf(var + 1e-5f);

    float4 gg = ((const float4*)gamma)[li];
    float4 be = ((const float4*)beta)[li];
    float ox = fmaxf(fmaf((acc.x - mu) * rstd, gg.x, be.x), 0.0f);
    float oy = fmaxf(fmaf((acc.y - mu) * rstd, gg.y, be.y), 0.0f);
    float oz = fmaxf(fmaf((acc.z - mu) * rstd, gg.z, be.z), 0.0f);
    float ow = fmaxf(fmaf((acc.w - mu) * rstd, gg.w, be.w), 0.0f);
    if (half == 0){
        if (OUT_BF16){
            uint2 o;
            o.x = f2bfbits(ox) | (f2bfbits(oy) << 16);
            o.y = f2bfbits(oz) | (f2bfbits(ow) << 16);
            ((uint2*)outv)[(size_t)node * 32 + li] = o;
        } else {
            floatx4 o = {ox, oy, oz, ow};
            __builtin_nontemporal_store(o, (floatx4*)outv + (size_t)node * 32 + li);
        }
    }
}

extern "C" void kernel_launch(void* const* d_in, const int* in_sizes, int n_in,
                              void* d_out, int out_size, void* d_ws, size_t ws_size,
                              hipStream_t stream){
    const float* x   = (const float*)d_in[0];
    const int*   ei  = (const int*)d_in[1];
    const float* W1  = (const float*)d_in[2];
    const float* b1  = (const float*)d_in[3];
    const float* g1  = (const float*)d_in[4];
    const float* be1 = (const float*)d_in[5];
    const float* W2  = (const float*)d_in[6];
    const float* b2  = (const float*)d_in[7];
    const float* g2  = (const float*)d_in[8];
    const float* be2 = (const float*)d_in[9];
    float* out = (float*)d_out;

    const int N = in_sizes[0] / D;
    const int E = in_sizes[1] / 2;
    const int* src = ei;
    const int* dst = ei + E;

    char* w = (char*)d_ws;
    size_t off = 0;
    auto alloc = [&](size_t bytes) -> char* {
        char* p = w + off;
        off = (off + bytes + 255) & ~(size_t)255;
        return p;
    };
    const int nchunk = (N + 2047) / 2048;
    const int NBK = (N + (1 << NBSHIFT) - 1) >> NBSHIFT;
    int*            deg      = (int*)alloc((size_t)N * 4);
    float*          dinv     = (float*)alloc((size_t)N * 4);
    int*            rowStart = (int*)alloc((size_t)(N + 1) * 4);
    int*            bsum     = (int*)alloc((size_t)nchunk * 4);
    int*            bcur     = (int*)alloc((size_t)NBK * 4);
    uint2*          edge2    = (uint2*)alloc((size_t)E * 8);
    int*            csr      = (int*)alloc((size_t)E * 4);
    unsigned short* wt1      = (unsigned short*)alloc(16384 * 2);
    unsigned short* wt2      = (unsigned short*)alloc(16384 * 2);
    unsigned short* h        = (unsigned short*)alloc((size_t)N * D * 2);
    unsigned short* hmid     = (unsigned short*)d_out;  // bf16 mid activation in d_out (25.6 of 51.2 MB)

    (void)hipMemsetAsync(deg, 0, (size_t)N * 4, stream);

    int gE = (E + 255) / 256;
    int gB = (E + EPB - 1) / EPB;
    int gG = (N + 63) / 64;
    int gA = (N + 3) / 4;

    k_deg   <<<gE, 256, 0, stream>>>(dst, deg, E);
    k_part  <<<nchunk, 256, 0, stream>>>(deg, bsum, N);
    k_ssum  <<<1, 256, 0, stream>>>(bsum, nchunk, rowStart + N);
    k_final <<<nchunk, 256, 0, stream>>>(deg, bsum, rowStart, dinv, bcur, N);
    k_bucket<<<gB, 256, 0, stream>>>(src, dst, bcur, edge2, NBK, E);
    k_csr   <<<NBK, 256, 0, stream>>>(edge2, rowStart, csr, N);
    k_wtrans<<<128, 256, 0, stream>>>(W1, W2, wt1, wt2);

    // layer 1: gemm(x) -> h ; agg -> hmid (bf16, in d_out)
    k_gemm<false><<<gG, 256, 0, stream>>>(x, wt1, h, N);
    k_agg<true>  <<<gA, 256, 0, stream>>>(h, rowStart, csr, dinv, b1, g1, be1, hmid, N);
    // layer 2: gemm(hmid) -> h ; agg -> out (fp32, nontemporal)
    k_gemm<true> <<<gG, 256, 0, stream>>>(hmid, wt2, h, N);
    k_agg<false> <<<gA, 256, 0, stream>>>(h, rowStart, csr, dinv, b2, g2, be2, out, N);
}

// Round 7
// 412.509 us; speedup vs baseline: 2.0823x; 1.1525x over previous
//
#include <hip/hip_runtime.h>

#define D 128
#define NBSHIFT 10          // 1024 nodes per bucket
#define NB (1 << NBSHIFT)
#define EPB 2048            // edges per k_bucket block

typedef __attribute__((ext_vector_type(8))) short bf16x8;
typedef __attribute__((ext_vector_type(4))) float floatx4;

__device__ __forceinline__ float bflo(unsigned int u){ return __uint_as_float(u << 16); }
__device__ __forceinline__ float bfhi(unsigned int u){ return __uint_as_float(u & 0xffff0000u); }
__device__ __forceinline__ unsigned int f2bfbits(float f){
    unsigned int x = __float_as_uint(f);
    return (x + 0x7fffu + ((x >> 16) & 1u)) >> 16;  // RNE, finite inputs
}

// ---- bucket counts: LDS histogram, 98 global adds per block ----
__global__ __launch_bounds__(256) void k_bcount(const int* __restrict__ dst, int* __restrict__ bcnt, int E){
    __shared__ int hist[128];
    int t = threadIdx.x;
    int base = blockIdx.x * EPB;
    if (t < 128) hist[t] = 0;
    __syncthreads();
#pragma unroll
    for (int j = 0; j < 8; ++j){
        int e = base + j * 256 + t;
        if (e < E) atomicAdd(&hist[dst[e] >> NBSHIFT], 1);
    }
    __syncthreads();
    if (t < 128 && hist[t] > 0) atomicAdd(&bcnt[t], hist[t]);
}

// ---- tiny scan of bucket counts -> bases + cursors; rowStart[N]=E ----
__global__ void k_bscan(const int* __restrict__ bcnt, int* __restrict__ bbase, int* __restrict__ bcur,
                        int* __restrict__ rowStartN, int NBK){
    if (threadIdx.x == 0){
        int run = 0;
        for (int b = 0; b < NBK; ++b){ bbase[b] = run; bcur[b] = run; run += bcnt[b]; }
        bbase[NBK] = run;
        *rowStartN = run;
    }
}

// ---- pass 1: LDS-staged partition of edges into dst-buckets; packed uint32 ----
// pack = src | (dstLow << 20)   (requires N < 2^20)
__global__ __launch_bounds__(256) void k_bucket(const int* __restrict__ src, const int* __restrict__ dst,
                                                int* __restrict__ bcur, unsigned int* __restrict__ edge1,
                                                int NBK, int E){
    __shared__ int hist[128], lstart[128], lcur[128], gbase[128];
    __shared__ unsigned int stage[EPB];
    int t = threadIdx.x;
    int base = blockIdx.x * EPB;
    int tot = min(EPB, E - base);
    if (t < 128) hist[t] = 0;
    __syncthreads();

    unsigned int ent[8]; int bk[8]; int cnt = 0;
#pragma unroll
    for (int j = 0; j < 8; ++j){
        int e = base + j * 256 + t;
        if (e < base + tot){
            unsigned s = (unsigned)src[e], d = (unsigned)dst[e];
            ent[cnt] = s | ((d & (NB - 1)) << 20);
            bk[cnt] = (int)(d >> NBSHIFT);
            atomicAdd(&hist[bk[cnt]], 1);
            ++cnt;
        }
    }
    __syncthreads();
    if (t < 128) lstart[t] = hist[t];
    __syncthreads();
    for (int off = 1; off < 128; off <<= 1){
        int v = 0;
        if (t < 128 && t >= off) v = lstart[t - off];
        __syncthreads();
        if (t < 128) lstart[t] += v;
        __syncthreads();
    }
    if (t < 128){
        int ex = lstart[t] - hist[t];
        lstart[t] = ex;
        lcur[t] = ex;
        if (t < NBK && hist[t] > 0) gbase[t] = atomicAdd(&bcur[t], hist[t]);
    }
    __syncthreads();
    for (int j = 0; j < cnt; ++j){
        int pos = atomicAdd(&lcur[bk[j]], 1);
        stage[pos] = ent[j];
    }
    __syncthreads();
    for (int i = t; i < tot; i += 256){
        unsigned int e1 = stage[i];
        int b = (int)((e1 >> 20) & (NB - 1));
        // recover bucket: need full dst bucket id — stored via position? No: bucket is
        // identified by which lstart window i falls in. Find b by the staged grouping:
        // stage is grouped by bucket; b from binary search would be slow. Instead we
        // kept only dstLow in the pack, so recompute bucket via lstart windows:
        // linear scan is too slow -> we store bucket implicitly: i >= lstart[b] boundary.
        // Use the fact that lstart is sorted: binary search over 128 entries (7 steps).
        int lo = 0, hi = 127;
        while (lo < hi){
            int midb = (lo + hi + 1) >> 1;
            if (lstart[midb] <= i) lo = midb; else hi = midb - 1;
        }
        b = lo;
        edge1[gbase[b] + (i - lstart[b])] = e1;
    }
}

// ---- pass 2: per-bucket degree hist + scan + CSR scatter (all LDS) ----
__global__ __launch_bounds__(1024) void k_csr2(const unsigned int* __restrict__ edge1,
                                               const int* __restrict__ bbase,
                                               int* __restrict__ rowStart, float* __restrict__ dinv,
                                               int* __restrict__ csr, int N){
    __shared__ int hist[NB];
    __shared__ int sc[NB];
    int b = blockIdx.x, t = threadIdx.x;
    int nbase = b << NBSHIFT;
    int nn = min(N - nbase, NB);
    int ebeg = bbase[b], eend = bbase[b + 1];

    if (t < NB) hist[t] = 0;
    __syncthreads();
    for (int i = ebeg + t; i < eend; i += 1024)
        atomicAdd(&hist[edge1[i] >> 20], 1);
    __syncthreads();
    if (t < NB) sc[t] = hist[t];
    __syncthreads();
    for (int off = 1; off < NB; off <<= 1){
        int v = (t >= off && t < NB) ? sc[t - off] : 0;
        __syncthreads();
        if (t < NB) sc[t] += v;
        __syncthreads();
    }
    // sc = inclusive; cursor/global offset = ebeg + (sc - hist)
    if (t < NB){
        int cur = ebeg + sc[t] - hist[t];
        sc[t] = cur;
        if (t < nn){
            rowStart[nbase + t] = cur;
            dinv[nbase + t] = rsqrtf((float)hist[t] + 1.0f);  // +1 self-loop
        }
    }
    __syncthreads();
    for (int i = ebeg + t; i < eend; i += 1024){
        unsigned int p = edge1[i];
        int pos = atomicAdd(&sc[p >> 20], 1);
        csr[pos] = (int)(p & 0xFFFFFu);
    }
}

// ---- transpose + fp32->bf16 weights ----
__global__ __launch_bounds__(256) void k_wtrans(const float* __restrict__ W1,
                                                const float* __restrict__ W2,
                                                unsigned short* __restrict__ Wt1,
                                                unsigned short* __restrict__ Wt2){
    int i = blockIdx.x * 256 + threadIdx.x;
    const float* Ws; unsigned short* Wd; int j = i;
    if (i < 16384){ Ws = W1; Wd = Wt1; } else { Ws = W2; Wd = Wt2; j -= 16384; }
    int k = j >> 7, n = j & 127;
    Wd[n * 128 + k] = (unsigned short)f2bfbits(Ws[k * 128 + n]);
}

// ---- bf16 MFMA GEMM, templated on A dtype; H stored bf16 ----
template<bool A_BF16>
__global__ __launch_bounds__(256) void k_gemm(const void* __restrict__ Av,
                                              const unsigned short* __restrict__ Wt,
                                              unsigned short* __restrict__ Hout, int Nrows){
    int wave = threadIdx.x >> 6, lane = threadIdx.x & 63;
    int m = lane & 15, quad = lane >> 4;
    int row0 = blockIdx.x * 64 + wave * 16;
    int arow = row0 + m;
    int arowc = arow < Nrows ? arow : Nrows - 1;

    bf16x8 a[4];
    if (A_BF16){
        const unsigned short* Ap = (const unsigned short*)Av + (size_t)arowc * D + quad * 8;
#pragma unroll
        for (int kt = 0; kt < 4; ++kt) a[kt] = *(const bf16x8*)(Ap + kt * 32);
    } else {
        const float* Ap = (const float*)Av + (size_t)arowc * D + quad * 8;
#pragma unroll
        for (int kt = 0; kt < 4; ++kt){
            float4 v0 = *(const float4*)(Ap + kt * 32);
            float4 v1 = *(const float4*)(Ap + kt * 32 + 4);
            bf16x8 af;
            af[0] = (short)f2bfbits(v0.x); af[1] = (short)f2bfbits(v0.y);
            af[2] = (short)f2bfbits(v0.z); af[3] = (short)f2bfbits(v0.w);
            af[4] = (short)f2bfbits(v1.x); af[5] = (short)f2bfbits(v1.y);
            af[6] = (short)f2bfbits(v1.z); af[7] = (short)f2bfbits(v1.w);
            a[kt] = af;
        }
    }

    floatx4 acc[8];
#pragma unroll
    for (int nt = 0; nt < 8; ++nt) acc[nt] = (floatx4){0.f, 0.f, 0.f, 0.f};

    const unsigned short* Bp = Wt + m * D + quad * 8;
#pragma unroll
    for (int kt = 0; kt < 4; ++kt){
        bf16x8 bk[8];
#pragma unroll
        for (int nt = 0; nt < 8; ++nt) bk[nt] = *(const bf16x8*)(Bp + nt * 16 * D + kt * 32);
#pragma unroll
        for (int nt = 0; nt < 8; ++nt)
            acc[nt] = __builtin_amdgcn_mfma_f32_16x16x32_bf16(a[kt], bk[nt], acc[nt], 0, 0, 0);
    }
#pragma unroll
    for (int nt = 0; nt < 8; ++nt){
#pragma unroll
        for (int r = 0; r < 4; ++r){
            int rr = row0 + quad * 4 + r;
            if (rr < Nrows) Hout[(size_t)rr * D + nt * 16 + m] = (unsigned short)f2bfbits(acc[nt][r]);
        }
    }
}

// ---- fused gather-aggregate + bias + LayerNorm + ReLU ----
template<bool OUT_BF16>
__global__ __launch_bounds__(256) void k_agg(const unsigned short* __restrict__ h,
                                             const int* __restrict__ rowStart,
                                             const int* __restrict__ csr,
                                             const float* __restrict__ dinv,
                                             const float* __restrict__ bias,
                                             const float* __restrict__ gamma,
                                             const float* __restrict__ beta,
                                             void* __restrict__ outv, int N){
    int node = blockIdx.x * 4 + (threadIdx.x >> 6);
    if (node >= N) return;
    int lane = threadIdx.x & 63;
    int half = lane >> 5, li = lane & 31;   // lane owns channels 4*li..4*li+3
    const uint2* hv = (const uint2*)h;

    float dv = dinv[node];
    float4 acc = {0.f, 0.f, 0.f, 0.f};
    if (half == 0){
        uint2 hs = hv[(size_t)node * 32 + li];
        float w0 = dv * dv;
        acc.x = bflo(hs.x) * w0; acc.y = bfhi(hs.x) * w0;
        acc.z = bflo(hs.y) * w0; acc.w = bfhi(hs.y) * w0;
    }

    int start = rowStart[node], end = rowStart[node + 1];
    int mid = start + ((end - start + 1) >> 1);
    int i    = half ? mid : start;
    int iend = half ? end : mid;

    for (; i + 4 <= iend; i += 4){
        int s0 = csr[i], s1 = csr[i + 1], s2 = csr[i + 2], s3 = csr[i + 3];
        uint2 h0 = hv[(size_t)s0 * 32 + li];
        uint2 h1 = hv[(size_t)s1 * 32 + li];
        uint2 h2 = hv[(size_t)s2 * 32 + li];
        uint2 h3 = hv[(size_t)s3 * 32 + li];
        float w0 = dinv[s0] * dv, w1 = dinv[s1] * dv, w2 = dinv[s2] * dv, w3 = dinv[s3] * dv;
        acc.x = fmaf(bflo(h0.x), w0, acc.x); acc.y = fmaf(bfhi(h0.x), w0, acc.y);
        acc.z = fmaf(bflo(h0.y), w0, acc.z); acc.w = fmaf(bfhi(h0.y), w0, acc.w);
        acc.x = fmaf(bflo(h1.x), w1, acc.x); acc.y = fmaf(bfhi(h1.x), w1, acc.y);
        acc.z = fmaf(bflo(h1.y), w1, acc.z); acc.w = fmaf(bfhi(h1.y), w1, acc.w);
        acc.x = fmaf(bflo(h2.x), w2, acc.x); acc.y = fmaf(bfhi(h2.x), w2, acc.y);
        acc.z = fmaf(bflo(h2.y), w2, acc.z); acc.w = fmaf(bfhi(h2.y), w2, acc.w);
        acc.x = fmaf(bflo(h3.x), w3, acc.x); acc.y = fmaf(bfhi(h3.x), w3, acc.y);
        acc.z = fmaf(bflo(h3.y), w3, acc.z); acc.w = fmaf(bfhi(h3.y), w3, acc.w);
    }
    for (; i < iend; ++i){
        int s = csr[i];
        float ws = dinv[s] * dv;
        uint2 hs = hv[(size_t)s * 32 + li];
        acc.x = fmaf(bflo(hs.x), ws, acc.x); acc.y = fmaf(bfhi(hs.x), ws, acc.y);
        acc.z = fmaf(bflo(hs.y), ws, acc.z); acc.w = fmaf(bfhi(hs.y), ws, acc.w);
    }

    acc.x += __shfl_xor(acc.x, 32, 64);
    acc.y += __shfl_xor(acc.y, 32, 64);
    acc.z += __shfl_xor(acc.z, 32, 64);
    acc.w += __shfl_xor(acc.w, 32, 64);

    float4 bb = ((const float4*)bias)[li];
    acc.x += bb.x; acc.y += bb.y; acc.z += bb.z; acc.w += bb.w;

    float s1 = acc.x + acc.y + acc.z + acc.w;
    float s2 = acc.x * acc.x + acc.y * acc.y + acc.z * acc.z + acc.w * acc.w;
#pragma unroll
    for (int off = 16; off > 0; off >>= 1){
        s1 += __shfl_xor(s1, off, 64);
        s2 += __shfl_xor(s2, off, 64);
    }
    float mu = s1 * (1.0f / 128.0f);
    float var = s2 * (1.0f / 128.0f) - mu * mu;
    float rstd = rsqrtf(var + 1e-5f);

    float4 gg = ((const float4*)gamma)[li];
    float4 be = ((const float4*)beta)[li];
    float ox = fmaxf(fmaf((acc.x - mu) * rstd, gg.x, be.x), 0.0f);
    float oy = fmaxf(fmaf((acc.y - mu) * rstd, gg.y, be.y), 0.0f);
    float oz = fmaxf(fmaf((acc.z - mu) * rstd, gg.z, be.z), 0.0f);
    float ow = fmaxf(fmaf((acc.w - mu) * rstd, gg.w, be.w), 0.0f);
    if (half == 0){
        if (OUT_BF16){
            uint2 o;
            o.x = f2bfbits(ox) | (f2bfbits(oy) << 16);
            o.y = f2bfbits(oz) | (f2bfbits(ow) << 16);
            ((uint2*)outv)[(size_t)node * 32 + li] = o;
        } else {
            floatx4 o = {ox, oy, oz, ow};
            __builtin_nontemporal_store(o, (floatx4*)outv + (size_t)node * 32 + li);
        }
    }
}

extern "C" void kernel_launch(void* const* d_in, const int* in_sizes, int n_in,
                              void* d_out, int out_size, void* d_ws, size_t ws_size,
                              hipStream_t stream){
    const float* x   = (const float*)d_in[0];
    const int*   ei  = (const int*)d_in[1];
    const float* W1  = (const float*)d_in[2];
    const float* b1  = (const float*)d_in[3];
    const float* g1  = (const float*)d_in[4];
    const float* be1 = (const float*)d_in[5];
    const float* W2  = (const float*)d_in[6];
    const float* b2  = (const float*)d_in[7];
    const float* g2  = (const float*)d_in[8];
    const float* be2 = (const float*)d_in[9];
    float* out = (float*)d_out;

    const int N = in_sizes[0] / D;
    const int E = in_sizes[1] / 2;
    const int* src = ei;
    const int* dst = ei + E;

    char* w = (char*)d_ws;
    size_t off = 0;
    auto alloc = [&](size_t bytes) -> char* {
        char* p = w + off;
        off = (off + bytes + 255) & ~(size_t)255;
        return p;
    };
    const int NBK = (N + NB - 1) >> NBSHIFT;
    int*            bcnt     = (int*)alloc((size_t)NBK * 4);
    int*            bbase    = (int*)alloc((size_t)(NBK + 1) * 4);
    int*            bcur     = (int*)alloc((size_t)NBK * 4);
    int*            rowStart = (int*)alloc((size_t)(N + 1) * 4);
    float*          dinv     = (float*)alloc((size_t)N * 4);
    unsigned int*   edge1    = (unsigned int*)alloc((size_t)E * 4);
    int*            csr      = (int*)alloc((size_t)E * 4);
    unsigned short* wt1      = (unsigned short*)alloc(16384 * 2);
    unsigned short* wt2      = (unsigned short*)alloc(16384 * 2);
    unsigned short* h        = (unsigned short*)alloc((size_t)N * D * 2);
    unsigned short* hmid     = (unsigned short*)d_out;  // bf16 mid activation in d_out

    (void)hipMemsetAsync(bcnt, 0, (size_t)NBK * 4, stream);

    int gB = (E + EPB - 1) / EPB;
    int gG = (N + 63) / 64;
    int gA = (N + 3) / 4;

    k_bcount<<<gB, 256, 0, stream>>>(dst, bcnt, E);
    k_bscan <<<1, 64, 0, stream>>>(bcnt, bbase, bcur, rowStart + N, NBK);
    k_bucket<<<gB, 256, 0, stream>>>(src, dst, bcur, edge1, NBK, E);
    k_csr2  <<<NBK, 1024, 0, stream>>>(edge1, bbase, rowStart, dinv, csr, N);
    k_wtrans<<<128, 256, 0, stream>>>(W1, W2, wt1, wt2);

    // layer 1: gemm(x) -> h ; agg -> hmid (bf16, in d_out)
    k_gemm<false><<<gG, 256, 0, stream>>>(x, wt1, h, N);
    k_agg<true>  <<<gA, 256, 0, stream>>>(h, rowStart, csr, dinv, b1, g1, be1, hmid, N);
    // layer 2: gemm(hmid) -> h ; agg -> out (fp32, nontemporal)
    k_gemm<true> <<<gG, 256, 0, stream>>>(hmid, wt2, h, N);
    k_agg<false> <<<gA, 256, 0, stream>>>(h, rowStart, csr, dinv, b2, g2, be2, out, N);
}